// Round 2
// baseline (1088.968 us; speedup 1.0000x reference)
//
#include <hip/hip_runtime.h>
#include <hip/hip_bf16.h>
#include <cstdint>

// Problem constants (from reference setup_inputs): N=M=8192, F=H=512, V=3.
#define NROWS 8192
#define MDIM  8192
#define FDIM  512
#define HDIM  512

typedef __bf16 bf16x8_t __attribute__((ext_vector_type(8)));
typedef float  f32x4_t  __attribute__((ext_vector_type(4)));
typedef int    i32x4_t  __attribute__((ext_vector_type(4)));

__device__ __forceinline__ unsigned short f2bf(float f) {
    uint32_t u = __float_as_uint(f);
    u = (u + 0x7fffu + ((u >> 16) & 1u)) >> 16;   // RNE
    return (unsigned short)u;
}

// async global->LDS, 16B per lane; LDS dest = uniform base + lane*16
__device__ __forceinline__ void g2l16(const unsigned short* g, unsigned short* l) {
    __builtin_amdgcn_global_load_lds(
        (const __attribute__((address_space(1))) void*)g,
        (__attribute__((address_space(3))) void*)l,
        16, 0, 0);
}

// ---------------- elementwise fp32 -> bf16 convert ----------------
__global__ void k_cvt(const float4* __restrict__ src, ushort4* __restrict__ dst, int n4) {
    int i = blockIdx.x * blockDim.x + threadIdx.x;
    if (i < n4) {
        float4 f = src[i];
        ushort4 u;
        u.x = f2bf(f.x); u.y = f2bf(f.y); u.z = f2bf(f.z); u.w = f2bf(f.w);
        dst[i] = u;
    }
}

// ---------------- transpose fp32 [R][C] -> bf16 [C][R] ----------------
__global__ void k_transpose(const float* __restrict__ src, unsigned short* __restrict__ dst,
                            int R, int C) {
    __shared__ float t[32][33];
    int c0 = blockIdx.x * 32, r0 = blockIdx.y * 32;
    #pragma unroll
    for (int k = 0; k < 32; k += 8)
        t[threadIdx.y + k][threadIdx.x] =
            src[(size_t)(r0 + threadIdx.y + k) * C + c0 + threadIdx.x];
    __syncthreads();
    #pragma unroll
    for (int k = 0; k < 32; k += 8)
        dst[(size_t)(c0 + threadIdx.y + k) * R + r0 + threadIdx.x] =
            f2bf(t[threadIdx.x][threadIdx.y + k]);
}

// ---------------- bf16 GEMM, C[row][col] = sum_k A[row][k]*B[col][k] ----------------
// 128x128 tile, BK=64, 256 threads = 4 waves, each wave a 64x64 quadrant (4x4 MFMA tiles).
// MODE 0: Cb = bf16(elu(acc))                      (q / k GEMMs)
// MODE 1: Cb = bf16(acc), atomicAdd row sum(acc^2) into norms  (att GEMM)
// MODE 2: Cf += acc / max(sqrt(norms[row]), eps)   (att @ z GEMM)
template<int MODE>
__global__ __launch_bounds__(256, 2)
void k_gemm_bt(const unsigned short* __restrict__ A, int lda,
               const unsigned short* __restrict__ B, int ldb, int K,
               unsigned short* __restrict__ Cb,
               float* __restrict__ Cf, int ldc,
               float* __restrict__ norms) {
    __shared__ unsigned short As[128 * 64];
    __shared__ unsigned short Bs[128 * 64];
    const int tid  = threadIdx.x;
    const int lane = tid & 63;
    const int w    = tid >> 6;
    const int wr   = w >> 1, wc = w & 1;
    const int row0 = blockIdx.y * 128;
    const int col0 = blockIdx.x * 128;
    const int quad = lane >> 4;
    const int l15  = lane & 15;
    const int srow = lane >> 3;          // 0..7 within a wave staging call
    const int scol = (lane & 7) * 8;     // bf16 elems (16B chunks)
    const int wbase = w * 4;

    f32x4_t acc[4][4] = {};

    for (int k0 = 0; k0 < K; k0 += 64) {
        __syncthreads();   // all waves done reading previous LDS tile
        #pragma unroll
        for (int c = 0; c < 4; ++c) {
            int rr = (wbase + c) * 8 + srow;   // 0..127
            g2l16(A + (size_t)(row0 + rr) * lda + k0 + scol, &As[(wbase + c) * 512]);
            g2l16(B + (size_t)(col0 + rr) * ldb + k0 + scol, &Bs[(wbase + c) * 512]);
        }
        asm volatile("s_waitcnt vmcnt(0)" ::: "memory");
        __syncthreads();
        #pragma unroll
        for (int kk = 0; kk < 2; ++kk) {
            bf16x8_t af[4], bfr[4];
            #pragma unroll
            for (int i = 0; i < 4; ++i) {
                int r = wr * 64 + i * 16 + l15;
                af[i] = __builtin_bit_cast(bf16x8_t,
                        *(const i32x4_t*)&As[r * 64 + kk * 32 + quad * 8]);
            }
            #pragma unroll
            for (int j = 0; j < 4; ++j) {
                int r = wc * 64 + j * 16 + l15;
                bfr[j] = __builtin_bit_cast(bf16x8_t,
                        *(const i32x4_t*)&Bs[r * 64 + kk * 32 + quad * 8]);
            }
            #pragma unroll
            for (int i = 0; i < 4; ++i)
                #pragma unroll
                for (int j = 0; j < 4; ++j)
                    acc[i][j] = __builtin_amdgcn_mfma_f32_16x16x32_bf16(
                        af[i], bfr[j], acc[i][j], 0, 0, 0);
        }
    }

    // C/D layout (m89-verified): col = lane&15, row = (lane>>4)*4 + reg
    if (MODE == 0) {
        #pragma unroll
        for (int i = 0; i < 4; ++i) {
            int rb = row0 + wr * 64 + i * 16 + quad * 4;
            #pragma unroll
            for (int j = 0; j < 4; ++j) {
                int col = col0 + wc * 64 + j * 16 + l15;
                #pragma unroll
                for (int r = 0; r < 4; ++r) {
                    float v = acc[i][j][r];
                    v = v > 0.f ? v : expm1f(v);
                    Cb[(size_t)(rb + r) * ldc + col] = f2bf(v);
                }
            }
        }
    } else if (MODE == 1) {
        float rs[4][4] = {};
        #pragma unroll
        for (int i = 0; i < 4; ++i) {
            int rb = row0 + wr * 64 + i * 16 + quad * 4;
            #pragma unroll
            for (int j = 0; j < 4; ++j) {
                int col = col0 + wc * 64 + j * 16 + l15;
                #pragma unroll
                for (int r = 0; r < 4; ++r) {
                    float v = acc[i][j][r];
                    Cb[(size_t)(rb + r) * ldc + col] = f2bf(v);
                    rs[i][r] += v * v;
                }
            }
        }
        #pragma unroll
        for (int i = 0; i < 4; ++i)
            #pragma unroll
            for (int r = 0; r < 4; ++r) {
                float v = rs[i][r];
                v += __shfl_xor(v, 1);
                v += __shfl_xor(v, 2);
                v += __shfl_xor(v, 4);
                v += __shfl_xor(v, 8);
                if (l15 == 0)
                    atomicAdd(&norms[row0 + wr * 64 + i * 16 + quad * 4 + r], v);
            }
    } else {
        #pragma unroll
        for (int i = 0; i < 4; ++i) {
            #pragma unroll
            for (int r = 0; r < 4; ++r) {
                int row = row0 + wr * 64 + i * 16 + quad * 4 + r;
                float s = 1.f / fmaxf(sqrtf(norms[row]), 1e-12f);
                #pragma unroll
                for (int j = 0; j < 4; ++j) {
                    int col = col0 + wc * 64 + j * 16 + l15;
                    Cf[(size_t)row * ldc + col] += s * acc[i][j][r];
                }
            }
        }
    }
}

extern "C" void kernel_launch(void* const* d_in, const int* in_sizes, int n_in,
                              void* d_out, int out_size, void* d_ws, size_t ws_size,
                              hipStream_t stream) {
    const float* cz = (const float*)d_in[0];
    const float* zs = (const float*)d_in[1];
    const float* Wq = (const float*)d_in[2];
    const float* Wk = (const float*)d_in[3];
    int V = in_sizes[1] / (MDIM * FDIM);   // 3
    float* out = (float*)d_out;

    // ---- workspace layout (all sizes 256B-multiple) ----
    char* ws = (char*)d_ws;
    size_t off = 0;
    auto alloc = [&](size_t bytes) -> void* {
        void* p = ws + off;
        off += (bytes + 255) & ~(size_t)255;
        return p;
    };
    unsigned short* cz_bf  = (unsigned short*)alloc((size_t)NROWS * FDIM * 2);
    unsigned short* q_bf   = (unsigned short*)alloc((size_t)NROWS * HDIM * 2);
    unsigned short* k_bf   = (unsigned short*)alloc((size_t)MDIM  * HDIM * 2);
    unsigned short* zv_bf  = (unsigned short*)alloc((size_t)MDIM  * FDIM * 2);
    unsigned short* zvt_bf = (unsigned short*)alloc((size_t)FDIM  * MDIM * 2);
    unsigned short* wq_bf  = (unsigned short*)alloc((size_t)HDIM  * FDIM * 2);
    unsigned short* wk_bf  = (unsigned short*)alloc((size_t)HDIM  * FDIM * 2);
    float* norms           = (float*)alloc((size_t)NROWS * 4);
    // att slice: as many rows as fit in remaining ws (full 8192 rows = 128 MB bf16)
    size_t remain = ws_size > off ? ws_size - off : 0;
    int Nc = (int)(remain / ((size_t)MDIM * 2));
    if (Nc > NROWS) Nc = NROWS;
    Nc &= ~127;
    if (Nc < 128) Nc = 128;   // minimum viable slice
    unsigned short* att_bf = (unsigned short*)alloc((size_t)Nc * MDIM * 2);

    // ---- convert inputs to bf16 ----
    k_cvt<<<dim3(NROWS * FDIM / 4 / 256), 256, 0, stream>>>(
        (const float4*)cz, (ushort4*)cz_bf, NROWS * FDIM / 4);
    k_cvt<<<dim3(HDIM * FDIM / 4 / 256), 256, 0, stream>>>(
        (const float4*)Wq, (ushort4*)wq_bf, HDIM * FDIM / 4);
    k_cvt<<<dim3(HDIM * FDIM / 4 / 256), 256, 0, stream>>>(
        (const float4*)Wk, (ushort4*)wk_bf, HDIM * FDIM / 4);

    // q = elu(cz @ Wq^T)
    k_gemm_bt<0><<<dim3(HDIM / 128, NROWS / 128), 256, 0, stream>>>(
        cz_bf, FDIM, wq_bf, FDIM, FDIM, q_bf, nullptr, HDIM, nullptr);

    // out = common_z
    hipMemcpyAsync(out, cz, (size_t)NROWS * FDIM * 4, hipMemcpyDeviceToDevice, stream);

    for (int v = 0; v < V; ++v) {
        const float* zv = zs + (size_t)v * MDIM * FDIM;
        k_cvt<<<dim3(MDIM * FDIM / 4 / 256), 256, 0, stream>>>(
            (const float4*)zv, (ushort4*)zv_bf, MDIM * FDIM / 4);
        k_transpose<<<dim3(FDIM / 32, MDIM / 32), dim3(32, 8), 0, stream>>>(
            zv, zvt_bf, MDIM, FDIM);
        // k = elu(zv @ Wk^T)
        k_gemm_bt<0><<<dim3(HDIM / 128, MDIM / 128), 256, 0, stream>>>(
            zv_bf, FDIM, wk_bf, FDIM, FDIM, k_bf, nullptr, HDIM, nullptr);
        hipMemsetAsync(norms, 0, NROWS * 4, stream);
        for (int r0 = 0; r0 < NROWS; r0 += Nc) {
            int rows = NROWS - r0; if (rows > Nc) rows = Nc;
            // att slice = q[r0:r0+rows] @ k^T   (+ row sumsq -> norms)
            k_gemm_bt<1><<<dim3(MDIM / 128, rows / 128), 256, 0, stream>>>(
                q_bf + (size_t)r0 * HDIM, HDIM, k_bf, HDIM, HDIM,
                att_bf, nullptr, MDIM, norms + r0);
            // out[r0:r0+rows] += (att / norm) @ zv
            k_gemm_bt<2><<<dim3(FDIM / 128, rows / 128), 256, 0, stream>>>(
                att_bf, MDIM, zvt_bf, MDIM, MDIM,
                nullptr, out + (size_t)r0 * FDIM, FDIM, norms + r0);
        }
    }
}

// Round 3
// 546.040 us; speedup vs baseline: 1.9943x; 1.9943x over previous
//
#include <hip/hip_runtime.h>
#include <hip/hip_bf16.h>
#include <cstdint>

// Problem constants (from reference setup_inputs): N=M=8192, F=H=512, V=3.
#define NROWS 8192
#define MDIM  8192
#define FDIM  512
#define HDIM  512

typedef __bf16 bf16x8_t __attribute__((ext_vector_type(8)));
typedef float  f32x4_t  __attribute__((ext_vector_type(4)));
typedef int    i32x4_t  __attribute__((ext_vector_type(4)));

__device__ __forceinline__ unsigned short f2bf(float f) {
    uint32_t u = __float_as_uint(f);
    u = (u + 0x7fffu + ((u >> 16) & 1u)) >> 16;   // RNE
    return (unsigned short)u;
}
__device__ __forceinline__ float bf2f(unsigned short u) {
    return __uint_as_float((uint32_t)u << 16);
}

// async global->LDS, 16B per lane; LDS dest = uniform base + lane*16
__device__ __forceinline__ void g2l16(const unsigned short* g, unsigned short* l) {
    __builtin_amdgcn_global_load_lds(
        (const __attribute__((address_space(1))) void*)g,
        (__attribute__((address_space(3))) void*)l,
        16, 0, 0);
}

// ---------------- elementwise fp32 -> bf16 convert ----------------
__global__ void k_cvt(const float4* __restrict__ src, ushort4* __restrict__ dst, int n4) {
    int i = blockIdx.x * blockDim.x + threadIdx.x;
    if (i < n4) {
        float4 f = src[i];
        ushort4 u;
        u.x = f2bf(f.x); u.y = f2bf(f.y); u.z = f2bf(f.z); u.w = f2bf(f.w);
        dst[i] = u;
    }
}

// ---- fp32 [R][C] -> bf16 row-major [R][C] AND bf16 transposed [C][R] ----
__global__ void k_cvt_t(const float* __restrict__ src,
                        unsigned short* __restrict__ dst_n,
                        unsigned short* __restrict__ dst_t, int R, int C) {
    __shared__ unsigned short t[32][33];
    int c0 = blockIdx.x * 32, r0 = blockIdx.y * 32;
    #pragma unroll
    for (int k = 0; k < 32; k += 8) {
        unsigned short b = f2bf(src[(size_t)(r0 + threadIdx.y + k) * C + c0 + threadIdx.x]);
        dst_n[(size_t)(r0 + threadIdx.y + k) * C + c0 + threadIdx.x] = b;
        t[threadIdx.y + k][threadIdx.x] = b;
    }
    __syncthreads();
    #pragma unroll
    for (int k = 0; k < 32; k += 8)
        dst_t[(size_t)(c0 + threadIdx.y + k) * R + r0 + threadIdx.x] =
            t[threadIdx.x][threadIdx.y + k];
}

// ---------------- bf16 [R][C] -> bf16 transposed [C][R] ----------------
__global__ void k_t_bf(const unsigned short* __restrict__ src,
                       unsigned short* __restrict__ dst, int R, int C) {
    __shared__ unsigned short t[32][33];
    int c0 = blockIdx.x * 32, r0 = blockIdx.y * 32;
    #pragma unroll
    for (int k = 0; k < 32; k += 8)
        t[threadIdx.y + k][threadIdx.x] =
            src[(size_t)(r0 + threadIdx.y + k) * C + c0 + threadIdx.x];
    __syncthreads();
    #pragma unroll
    for (int k = 0; k < 32; k += 8)
        dst[(size_t)(c0 + threadIdx.y + k) * R + r0 + threadIdx.x] =
            t[threadIdx.x][threadIdx.y + k];
}

// ---- fp32 [rows][512] -> double-bf16 [rows][1024]: cols 0-511 hi, 512-1023 lo ----
__global__ void k_split(const float* __restrict__ src, unsigned short* __restrict__ dst, int n) {
    int i = blockIdx.x * blockDim.x + threadIdx.x;
    if (i < n) {
        int row = i >> 9, col = i & 511;
        float v = src[i];
        unsigned short hi = f2bf(v);
        unsigned short lo = f2bf(v - bf2f(hi));
        dst[(size_t)row * 1024 + col] = hi;
        dst[(size_t)row * 1024 + 512 + col] = lo;
    }
}

// ---------------- bf16 GEMM, C[row][col] = sum_k A[row][k]*B[col][k] ----------------
// 128x128 tile, BK=64, 256 threads = 4 waves. Split-K via blockIdx.z (kbeg = z*K).
// A k-index is wrapped by akmask (for double-bf16 B with K=1024, A wraps at 512).
// MODE 0: Cb = bf16(elu(acc))                             (q / k GEMMs)
// MODE 2: Cf[row][col] += acc / max(sqrt(max(n2,0)),eps)  (final out GEMM)
// MODE 3: atomicAdd(Cf[row][col], acc)                    (split-K G / Wvt GEMMs)
// MODE 4: atomicAdd(norms[row], sum_col acc*Q[row][col])  (n2 = (qG)·q rowwise)
template<int MODE>
__global__ __launch_bounds__(256, 2)
void k_gemm_bt(const unsigned short* __restrict__ A, int lda, int akmask,
               const unsigned short* __restrict__ B, int ldb, int K,
               unsigned short* __restrict__ Cb,
               float* __restrict__ Cf, int ldc,
               float* __restrict__ norms,
               const unsigned short* __restrict__ Q) {
    __shared__ unsigned short As[128 * 64];
    __shared__ unsigned short Bs[128 * 64];
    const int tid  = threadIdx.x;
    const int lane = tid & 63;
    const int w    = tid >> 6;
    const int wr   = w >> 1, wc = w & 1;
    const int row0 = blockIdx.y * 128;
    const int col0 = blockIdx.x * 128;
    const int quad = lane >> 4;
    const int l15  = lane & 15;
    const int srow = lane >> 3;          // 0..7 within a wave staging call
    const int scol = (lane & 7) * 8;     // bf16 elems (16B chunks)
    const int wbase = w * 4;

    f32x4_t acc[4][4] = {};
    const int kbeg = blockIdx.z * K;

    for (int k0 = kbeg; k0 < kbeg + K; k0 += 64) {
        __syncthreads();   // all waves done reading previous LDS tile
        const int ka = k0 & akmask;
        #pragma unroll
        for (int c = 0; c < 4; ++c) {
            int rr = (wbase + c) * 8 + srow;   // 0..127
            g2l16(A + (size_t)(row0 + rr) * lda + ka + scol, &As[(wbase + c) * 512]);
            g2l16(B + (size_t)(col0 + rr) * ldb + k0 + scol, &Bs[(wbase + c) * 512]);
        }
        asm volatile("s_waitcnt vmcnt(0)" ::: "memory");
        __syncthreads();
        #pragma unroll
        for (int kk = 0; kk < 2; ++kk) {
            bf16x8_t af[4], bfr[4];
            #pragma unroll
            for (int i = 0; i < 4; ++i) {
                int r = wr * 64 + i * 16 + l15;
                af[i] = __builtin_bit_cast(bf16x8_t,
                        *(const i32x4_t*)&As[r * 64 + kk * 32 + quad * 8]);
            }
            #pragma unroll
            for (int j = 0; j < 4; ++j) {
                int r = wc * 64 + j * 16 + l15;
                bfr[j] = __builtin_bit_cast(bf16x8_t,
                        *(const i32x4_t*)&Bs[r * 64 + kk * 32 + quad * 8]);
            }
            #pragma unroll
            for (int i = 0; i < 4; ++i)
                #pragma unroll
                for (int j = 0; j < 4; ++j)
                    acc[i][j] = __builtin_amdgcn_mfma_f32_16x16x32_bf16(
                        af[i], bfr[j], acc[i][j], 0, 0, 0);
        }
    }

    // C/D layout (m89-verified): col = lane&15, row = (lane>>4)*4 + reg
    if (MODE == 0) {
        #pragma unroll
        for (int i = 0; i < 4; ++i) {
            int rb = row0 + wr * 64 + i * 16 + quad * 4;
            #pragma unroll
            for (int j = 0; j < 4; ++j) {
                int col = col0 + wc * 64 + j * 16 + l15;
                #pragma unroll
                for (int r = 0; r < 4; ++r) {
                    float v = acc[i][j][r];
                    v = v > 0.f ? v : expm1f(v);
                    Cb[(size_t)(rb + r) * ldc + col] = f2bf(v);
                }
            }
        }
    } else if (MODE == 2) {
        #pragma unroll
        for (int i = 0; i < 4; ++i) {
            #pragma unroll
            for (int r = 0; r < 4; ++r) {
                int row = row0 + wr * 64 + i * 16 + quad * 4 + r;
                float s = 1.f / fmaxf(sqrtf(fmaxf(norms[row], 0.f)), 1e-12f);
                #pragma unroll
                for (int j = 0; j < 4; ++j) {
                    int col = col0 + wc * 64 + j * 16 + l15;
                    Cf[(size_t)row * ldc + col] += s * acc[i][j][r];
                }
            }
        }
    } else if (MODE == 3) {
        #pragma unroll
        for (int i = 0; i < 4; ++i) {
            int rb = row0 + wr * 64 + i * 16 + quad * 4;
            #pragma unroll
            for (int j = 0; j < 4; ++j) {
                int col = col0 + wc * 64 + j * 16 + l15;
                #pragma unroll
                for (int r = 0; r < 4; ++r)
                    atomicAdd(&Cf[(size_t)(rb + r) * ldc + col], acc[i][j][r]);
            }
        }
    } else if (MODE == 4) {
        float rs[4][4] = {};
        #pragma unroll
        for (int i = 0; i < 4; ++i) {
            int rb = row0 + wr * 64 + i * 16 + quad * 4;
            #pragma unroll
            for (int j = 0; j < 4; ++j) {
                int col = col0 + wc * 64 + j * 16 + l15;
                #pragma unroll
                for (int r = 0; r < 4; ++r)
                    rs[i][r] += acc[i][j][r] * bf2f(Q[(size_t)(rb + r) * ldc + col]);
            }
        }
        #pragma unroll
        for (int i = 0; i < 4; ++i)
            #pragma unroll
            for (int r = 0; r < 4; ++r) {
                float v = rs[i][r];
                v += __shfl_xor(v, 1);
                v += __shfl_xor(v, 2);
                v += __shfl_xor(v, 4);
                v += __shfl_xor(v, 8);
                if (l15 == 0)
                    atomicAdd(&norms[row0 + wr * 64 + i * 16 + quad * 4 + r], v);
            }
    }
}

extern "C" void kernel_launch(void* const* d_in, const int* in_sizes, int n_in,
                              void* d_out, int out_size, void* d_ws, size_t ws_size,
                              hipStream_t stream) {
    const float* cz = (const float*)d_in[0];
    const float* zs = (const float*)d_in[1];
    const float* Wq = (const float*)d_in[2];
    const float* Wk = (const float*)d_in[3];
    int V = in_sizes[1] / (MDIM * FDIM);   // 3
    float* out = (float*)d_out;
    const int NOMASK = 0x7fffffff;

    // ---- workspace layout ----
    char* ws = (char*)d_ws;
    size_t off = 0;
    auto alloc = [&](size_t bytes) -> void* {
        void* p = ws + off;
        off += (bytes + 255) & ~(size_t)255;
        return p;
    };
    unsigned short* cz_bf  = (unsigned short*)alloc((size_t)NROWS * FDIM * 2);
    unsigned short* q_bf   = (unsigned short*)alloc((size_t)NROWS * HDIM * 2);
    unsigned short* k_bf   = (unsigned short*)alloc((size_t)MDIM  * HDIM * 2);
    unsigned short* zv_bf  = (unsigned short*)alloc((size_t)MDIM  * FDIM * 2);
    unsigned short* zvt_bf = (unsigned short*)alloc((size_t)FDIM  * MDIM * 2);
    unsigned short* kT_bf  = (unsigned short*)alloc((size_t)HDIM  * MDIM * 2);
    unsigned short* wq_bf  = (unsigned short*)alloc((size_t)HDIM  * FDIM * 2);
    unsigned short* wk_bf  = (unsigned short*)alloc((size_t)HDIM  * FDIM * 2);
    float* Gf32            = (float*)alloc((size_t)HDIM * HDIM * 4);   // adjacent to
    float* Wvtf32          = (float*)alloc((size_t)FDIM * HDIM * 4);   // ...this (one memset)
    unsigned short* Gcat   = (unsigned short*)alloc((size_t)HDIM * 1024 * 2);
    unsigned short* Wvtcat = (unsigned short*)alloc((size_t)FDIM * 1024 * 2);
    float* n2              = (float*)alloc((size_t)NROWS * 4);

    // ---- convert inputs to bf16 ----
    k_cvt<<<dim3(NROWS * FDIM / 4 / 256), 256, 0, stream>>>(
        (const float4*)cz, (ushort4*)cz_bf, NROWS * FDIM / 4);
    k_cvt<<<dim3(HDIM * FDIM / 4 / 256), 256, 0, stream>>>(
        (const float4*)Wq, (ushort4*)wq_bf, HDIM * FDIM / 4);
    k_cvt<<<dim3(HDIM * FDIM / 4 / 256), 256, 0, stream>>>(
        (const float4*)Wk, (ushort4*)wk_bf, HDIM * FDIM / 4);

    // q = elu(cz @ Wq^T)   [N x H]
    k_gemm_bt<0><<<dim3(HDIM / 128, NROWS / 128, 1), 256, 0, stream>>>(
        cz_bf, FDIM, NOMASK, wq_bf, FDIM, FDIM, q_bf, nullptr, HDIM, nullptr, nullptr);

    // out = common_z
    hipMemcpyAsync(out, cz, (size_t)NROWS * FDIM * 4, hipMemcpyDeviceToDevice, stream);

    for (int v = 0; v < V; ++v) {
        const float* zv = zs + (size_t)v * MDIM * FDIM;
        // zv -> bf16 row-major + bf16 transposed [F][M]
        k_cvt_t<<<dim3(FDIM / 32, MDIM / 32), dim3(32, 8), 0, stream>>>(
            zv, zv_bf, zvt_bf, MDIM, FDIM);
        // k = elu(zv @ Wk^T)   [M x H]
        k_gemm_bt<0><<<dim3(HDIM / 128, MDIM / 128, 1), 256, 0, stream>>>(
            zv_bf, FDIM, NOMASK, wk_bf, FDIM, FDIM, k_bf, nullptr, HDIM, nullptr, nullptr);
        // kT [H][M]
        k_t_bf<<<dim3(HDIM / 32, MDIM / 32), dim3(32, 8), 0, stream>>>(
            k_bf, kT_bf, MDIM, HDIM);
        // G = k^T k  [H][H], Wvt = (k^T zv)^T = zv^T k  [F][H]  (split-K=16, fp32 atomics)
        hipMemsetAsync(Gf32, 0, (size_t)(HDIM * HDIM + FDIM * HDIM) * 4, stream);
        k_gemm_bt<3><<<dim3(HDIM / 128, HDIM / 128, 16), 256, 0, stream>>>(
            kT_bf, MDIM, NOMASK, kT_bf, MDIM, MDIM / 16, nullptr, Gf32, HDIM, nullptr, nullptr);
        k_gemm_bt<3><<<dim3(HDIM / 128, FDIM / 128, 16), 256, 0, stream>>>(
            zvt_bf, MDIM, NOMASK, kT_bf, MDIM, MDIM / 16, nullptr, Wvtf32, HDIM, nullptr, nullptr);
        // double-bf16 split: [rows][1024] = [hi | lo]
        k_split<<<dim3(HDIM * HDIM / 256), 256, 0, stream>>>(Gf32, Gcat, HDIM * HDIM);
        k_split<<<dim3(FDIM * HDIM / 256), 256, 0, stream>>>(Wvtf32, Wvtcat, FDIM * HDIM);
        // n2[r] = (q Gcat^T) . q  rowwise   (A wraps at 512, K=1024)
        hipMemsetAsync(n2, 0, NROWS * 4, stream);
        k_gemm_bt<4><<<dim3(HDIM / 128, NROWS / 128, 1), 256, 0, stream>>>(
            q_bf, HDIM, 511, Gcat, 1024, 1024, nullptr, nullptr, HDIM, n2, q_bf);
        // out += diag(1/max(sqrt(n2),eps)) * (q @ Wvtcat^T)
        k_gemm_bt<2><<<dim3(FDIM / 128, NROWS / 128, 1), 256, 0, stream>>>(
            q_bf, HDIM, 511, Wvtcat, 1024, 1024, nullptr, out, FDIM, n2, nullptr);
    }
}

// Round 4
// 305.634 us; speedup vs baseline: 3.5630x; 1.7866x over previous
//
#include <hip/hip_runtime.h>
#include <cstdint>

// Problem constants (from reference setup_inputs): N=M=8192, F=H=512, V=3.
#define NROWS 8192
#define MDIM  8192
#define FDIM  512
#define HDIM  512

typedef _Float16 f16x8_t __attribute__((ext_vector_type(8)));
typedef float    f32x4_t __attribute__((ext_vector_type(4)));
typedef int      i32x4_t __attribute__((ext_vector_type(4)));

__device__ __forceinline__ unsigned short f2h(float f) {
    return __builtin_bit_cast(unsigned short, (_Float16)f);
}
__device__ __forceinline__ float h2f(unsigned short u) {
    return (float)__builtin_bit_cast(_Float16, u);
}

// async global->LDS, 16B per lane; LDS dest = uniform base + lane*16
__device__ __forceinline__ void g2l16(const unsigned short* g, unsigned short* l) {
    __builtin_amdgcn_global_load_lds(
        (const __attribute__((address_space(1))) void*)g,
        (__attribute__((address_space(3))) void*)l, 16, 0, 0);
}

// ---------------- elementwise fp32 -> fp16 convert ----------------
__global__ void k_cvt(const float4* __restrict__ src, ushort4* __restrict__ dst, int n4) {
    int i = blockIdx.x * blockDim.x + threadIdx.x;
    if (i < n4) {
        float4 f = src[i];
        ushort4 u;
        u.x = f2h(f.x); u.y = f2h(f.y); u.z = f2h(f.z); u.w = f2h(f.w);
        dst[i] = u;
    }
}

// ---- fp32 [R][C] -> fp16 row-major [R][C] AND fp16 transposed [C][R], batched z ----
__global__ void k_cvt_t(const float* __restrict__ src, long sV,
                        unsigned short* __restrict__ dn, long nV,
                        unsigned short* __restrict__ dt, long tV, int R, int C) {
    src += (long)blockIdx.z * sV; dn += (long)blockIdx.z * nV; dt += (long)blockIdx.z * tV;
    __shared__ unsigned short t[32][33];
    int c0 = blockIdx.x * 32, r0 = blockIdx.y * 32;
    #pragma unroll
    for (int k = 0; k < 32; k += 8) {
        unsigned short b = f2h(src[(size_t)(r0 + threadIdx.y + k) * C + c0 + threadIdx.x]);
        dn[(size_t)(r0 + threadIdx.y + k) * C + c0 + threadIdx.x] = b;
        t[threadIdx.y + k][threadIdx.x] = b;
    }
    __syncthreads();
    #pragma unroll
    for (int k = 0; k < 32; k += 8)
        dt[(size_t)(c0 + threadIdx.y + k) * R + r0 + threadIdx.x] =
            t[threadIdx.x][threadIdx.y + k];
}

// ---------------- fp16 [R][C] -> fp16 transposed [C][R], batched z ----------------
__global__ void k_t_h(const unsigned short* __restrict__ src, long sV,
                      unsigned short* __restrict__ dst, long dV, int R, int C) {
    src += (long)blockIdx.z * sV; dst += (long)blockIdx.z * dV;
    __shared__ unsigned short t[32][33];
    int c0 = blockIdx.x * 32, r0 = blockIdx.y * 32;
    #pragma unroll
    for (int k = 0; k < 32; k += 8)
        t[threadIdx.y + k][threadIdx.x] =
            src[(size_t)(r0 + threadIdx.y + k) * C + c0 + threadIdx.x];
    __syncthreads();
    #pragma unroll
    for (int k = 0; k < 32; k += 8)
        dst[(size_t)(c0 + threadIdx.y + k) * R + r0 + threadIdx.x] =
            t[threadIdx.x][threadIdx.y + k];
}

// ---- reduce 8 split-K partials; rows<512 -> G fp16 [v][512][512],
//      rows>=512 -> Bfin fp16 [512][1536] (col = v*512 + h) ----
__global__ void k_rsplit(const float* __restrict__ GWp,
                         unsigned short* __restrict__ G,
                         unsigned short* __restrict__ Bfin, int n) {
    int i = blockIdx.x * blockDim.x + threadIdx.x;
    if (i >= n) return;
    int v = i / (1024 * 512);
    int rc = i - v * (1024 * 512);
    int row = rc >> 9, col = rc & 511;
    const float* p = GWp + (size_t)v * 8 * 1024 * 512 + rc;
    float s = 0.f;
    #pragma unroll
    for (int sl = 0; sl < 8; ++sl) s += p[(size_t)sl * 1024 * 512];
    if (row < 512) G[((size_t)v * 512 + row) * 512 + col] = f2h(s);
    else Bfin[(size_t)(row - 512) * 1536 + v * 512 + col] = f2h(s);
}

// ---- qs[r][v*512+h] = q[r][h] / max(sqrt(max(n2_v[r],0)), eps) ----
__global__ void k_scaleq(const unsigned short* __restrict__ q,
                         const float* __restrict__ n2,
                         unsigned short* __restrict__ qs) {
    int i = blockIdx.x * blockDim.x + threadIdx.x;  // NROWS*64 threads, 8 elems each
    int row = i >> 6, c8 = (i & 63) << 3;
    ushort4 a = *(const ushort4*)&q[(size_t)row * 512 + c8];
    ushort4 b = *(const ushort4*)&q[(size_t)row * 512 + c8 + 4];
    float qv[8] = {h2f(a.x), h2f(a.y), h2f(a.z), h2f(a.w),
                   h2f(b.x), h2f(b.y), h2f(b.z), h2f(b.w)};
    #pragma unroll
    for (int v = 0; v < 3; ++v) {
        float n = n2[v * NROWS + row];
        float s = 1.f / fmaxf(sqrtf(fmaxf(n, 0.f)), 1e-12f);
        ushort4 o0, o1;
        o0.x = f2h(s * qv[0]); o0.y = f2h(s * qv[1]);
        o0.z = f2h(s * qv[2]); o0.w = f2h(s * qv[3]);
        o1.x = f2h(s * qv[4]); o1.y = f2h(s * qv[5]);
        o1.z = f2h(s * qv[6]); o1.w = f2h(s * qv[7]);
        *(ushort4*)&qs[(size_t)row * 1536 + v * 512 + c8]     = o0;
        *(ushort4*)&qs[(size_t)row * 1536 + v * 512 + c8 + 4] = o1;
    }
}

// ---------------- fp16 GEMM, C[row][col] = sum_k A[row][k]*B[col][k] ----------------
// 128x128 tile, BK=64, 256 threads = 4 waves (64x64 quadrant each, 4x4 MFMA tiles).
// blockIdx.z: MODE3 -> (view, kslice); else view. Per-view strides aV/bV.
// MODE 0: Cb[view] = fp16(elu(acc))                 (q / k GEMMs)
// MODE 2: Cf = CZ + acc                             (final out GEMM, fp32)
// MODE 3: Cf[z] = acc  (per-(view,slice) partials)  (G / Wvt split-K GEMM)
// MODE 4: atomicAdd(norms[view][row], sum_col acc*Q[row][col])   (n2 = (qG).q)
template<int MODE>
__global__ __launch_bounds__(256, 2)
void k_gemm_bt(const unsigned short* __restrict__ A, int lda, long aV,
               const unsigned short* __restrict__ B, int ldb, long bV,
               int K, int kslices,
               unsigned short* __restrict__ Cb, long cbV,
               float* __restrict__ Cf, int ldc, long cfV,
               float* __restrict__ norms,
               const unsigned short* __restrict__ Q,
               const float* __restrict__ CZ) {
    const int z    = blockIdx.z;
    const int view = (MODE == 3) ? z / kslices : z;
    const int kbeg = (MODE == 3) ? (z % kslices) * K : 0;
    A += (long)view * aV;
    B += (long)view * bV;

    __shared__ unsigned short As[128 * 64];
    __shared__ unsigned short Bs[128 * 64];
    const int tid  = threadIdx.x;
    const int lane = tid & 63;
    const int w    = tid >> 6;
    const int wr   = w >> 1, wc = w & 1;
    const int row0 = blockIdx.y * 128;
    const int col0 = blockIdx.x * 128;
    const int quad = lane >> 4;
    const int l15  = lane & 15;
    const int srow = lane >> 3;
    const int scol = (lane & 7) * 8;
    const int wbase = w * 4;

    f32x4_t acc[4][4] = {};

    for (int k0 = kbeg; k0 < kbeg + K; k0 += 64) {
        __syncthreads();
        #pragma unroll
        for (int c = 0; c < 4; ++c) {
            int rr = (wbase + c) * 8 + srow;
            g2l16(A + (size_t)(row0 + rr) * lda + k0 + scol, &As[(wbase + c) * 512]);
            g2l16(B + (size_t)(col0 + rr) * ldb + k0 + scol, &Bs[(wbase + c) * 512]);
        }
        asm volatile("s_waitcnt vmcnt(0)" ::: "memory");
        __syncthreads();
        #pragma unroll
        for (int kk = 0; kk < 2; ++kk) {
            f16x8_t af[4], bfr[4];
            #pragma unroll
            for (int i = 0; i < 4; ++i) {
                int r = wr * 64 + i * 16 + l15;
                af[i] = __builtin_bit_cast(f16x8_t,
                        *(const i32x4_t*)&As[r * 64 + kk * 32 + quad * 8]);
            }
            #pragma unroll
            for (int j = 0; j < 4; ++j) {
                int r = wc * 64 + j * 16 + l15;
                bfr[j] = __builtin_bit_cast(f16x8_t,
                        *(const i32x4_t*)&Bs[r * 64 + kk * 32 + quad * 8]);
            }
            #pragma unroll
            for (int i = 0; i < 4; ++i)
                #pragma unroll
                for (int j = 0; j < 4; ++j)
                    acc[i][j] = __builtin_amdgcn_mfma_f32_16x16x32_f16(
                        af[i], bfr[j], acc[i][j], 0, 0, 0);
        }
    }

    // C/D layout (m89-verified): col = lane&15, row = (lane>>4)*4 + reg
    if (MODE == 0) {
        unsigned short* C = Cb + (long)view * cbV;
        #pragma unroll
        for (int i = 0; i < 4; ++i) {
            int rb = row0 + wr * 64 + i * 16 + quad * 4;
            #pragma unroll
            for (int j = 0; j < 4; ++j) {
                int col = col0 + wc * 64 + j * 16 + l15;
                #pragma unroll
                for (int r = 0; r < 4; ++r) {
                    float v = acc[i][j][r];
                    v = v > 0.f ? v : expm1f(v);
                    C[(size_t)(rb + r) * ldc + col] = f2h(v);
                }
            }
        }
    } else if (MODE == 2) {
        #pragma unroll
        for (int i = 0; i < 4; ++i) {
            #pragma unroll
            for (int r = 0; r < 4; ++r) {
                int row = row0 + wr * 64 + i * 16 + quad * 4 + r;
                #pragma unroll
                for (int j = 0; j < 4; ++j) {
                    int col = col0 + wc * 64 + j * 16 + l15;
                    Cf[(size_t)row * ldc + col] =
                        CZ[(size_t)row * ldc + col] + acc[i][j][r];
                }
            }
        }
    } else if (MODE == 3) {
        float* C = Cf + (long)z * cfV;
        #pragma unroll
        for (int i = 0; i < 4; ++i) {
            int rb = row0 + wr * 64 + i * 16 + quad * 4;
            #pragma unroll
            for (int j = 0; j < 4; ++j) {
                int col = col0 + wc * 64 + j * 16 + l15;
                #pragma unroll
                for (int r = 0; r < 4; ++r)
                    C[(size_t)(rb + r) * ldc + col] = acc[i][j][r];
            }
        }
    } else if (MODE == 4) {
        float* nptr = norms + (long)view * NROWS;
        float rs[4][4] = {};
        #pragma unroll
        for (int i = 0; i < 4; ++i) {
            int rb = row0 + wr * 64 + i * 16 + quad * 4;
            #pragma unroll
            for (int j = 0; j < 4; ++j) {
                int col = col0 + wc * 64 + j * 16 + l15;
                #pragma unroll
                for (int r = 0; r < 4; ++r)
                    rs[i][r] += acc[i][j][r] * h2f(Q[(size_t)(rb + r) * ldc + col]);
            }
        }
        #pragma unroll
        for (int i = 0; i < 4; ++i)
            #pragma unroll
            for (int r = 0; r < 4; ++r) {
                float v = rs[i][r];
                v += __shfl_xor(v, 1);
                v += __shfl_xor(v, 2);
                v += __shfl_xor(v, 4);
                v += __shfl_xor(v, 8);
                if (l15 == 0)
                    atomicAdd(&nptr[row0 + wr * 64 + i * 16 + quad * 4 + r], v);
            }
    }
}

extern "C" void kernel_launch(void* const* d_in, const int* in_sizes, int n_in,
                              void* d_out, int out_size, void* d_ws, size_t ws_size,
                              hipStream_t stream) {
    const float* cz = (const float*)d_in[0];
    const float* zs = (const float*)d_in[1];
    const float* Wq = (const float*)d_in[2];
    const float* Wk = (const float*)d_in[3];
    float* out = (float*)d_out;

    char* ws = (char*)d_ws;
    size_t off = 0;
    auto alloc = [&](size_t bytes) -> void* {
        void* p = ws + off;
        off += (bytes + 255) & ~(size_t)255;
        return p;
    };
    unsigned short* cz_h  = (unsigned short*)alloc((size_t)NROWS * FDIM * 2);   // 8 MB
    unsigned short* wq_h  = (unsigned short*)alloc((size_t)HDIM * FDIM * 2);
    unsigned short* wk_h  = (unsigned short*)alloc((size_t)HDIM * FDIM * 2);
    unsigned short* q_h   = (unsigned short*)alloc((size_t)NROWS * HDIM * 2);   // 8 MB
    unsigned short* zv_h  = (unsigned short*)alloc((size_t)3 * MDIM * FDIM * 2);  // 24 MB
    unsigned short* k_h   = (unsigned short*)alloc((size_t)3 * MDIM * HDIM * 2);  // 24 MB
    unsigned short* kzT   = (unsigned short*)alloc((size_t)3 * 1024 * MDIM * 2);  // 48 MB: [kT;zvT] per view
    float* GWp            = (float*)alloc((size_t)3 * 8 * 1024 * 512 * 4);        // 48 MB
    unsigned short* G     = (unsigned short*)alloc((size_t)3 * 512 * 512 * 2);
    unsigned short* Bfin  = (unsigned short*)alloc((size_t)512 * 1536 * 2);
    float* n2             = (float*)alloc((size_t)3 * NROWS * 4);
    unsigned short* qs    = (unsigned short*)alloc((size_t)NROWS * 1536 * 2);     // 24 MB

    const long MF = (long)MDIM * FDIM;   // 8192*512
    const long KZ = (long)1024 * MDIM;   // per-view kzT stride

    // 1-3: inputs -> fp16
    k_cvt<<<dim3(NROWS * FDIM / 4 / 256), 256, 0, stream>>>(
        (const float4*)cz, (ushort4*)cz_h, NROWS * FDIM / 4);
    k_cvt<<<dim3(HDIM * FDIM / 4 / 256), 256, 0, stream>>>(
        (const float4*)Wq, (ushort4*)wq_h, HDIM * FDIM / 4);
    k_cvt<<<dim3(HDIM * FDIM / 4 / 256), 256, 0, stream>>>(
        (const float4*)Wk, (ushort4*)wk_h, HDIM * FDIM / 4);

    // 4: q = elu(cz @ Wq^T)  [N][H]
    k_gemm_bt<0><<<dim3(4, 64, 1), 256, 0, stream>>>(
        cz_h, FDIM, 0, wq_h, FDIM, 0, FDIM, 0,
        q_h, 0, nullptr, HDIM, 0, nullptr, nullptr, nullptr);

    // 5: zs -> zv_h (row-major) + zvT into kzT upper half, all views
    k_cvt_t<<<dim3(FDIM / 32, MDIM / 32, 3), dim3(32, 8), 0, stream>>>(
        zs, MF, zv_h, MF, kzT + (size_t)512 * MDIM, KZ, MDIM, FDIM);

    // 6: k_v = elu(zv @ Wk^T)  [M][H], batched
    k_gemm_bt<0><<<dim3(4, 64, 3), 256, 0, stream>>>(
        zv_h, FDIM, MF, wk_h, FDIM, 0, FDIM, 0,
        k_h, MF, nullptr, HDIM, 0, nullptr, nullptr, nullptr);

    // 7: kT into kzT lower half, batched
    k_t_h<<<dim3(HDIM / 32, MDIM / 32, 3), dim3(32, 8), 0, stream>>>(
        k_h, MF, kzT, KZ, MDIM, HDIM);

    // 8: [G_v; Wvt_v] = [kT_v; zvT_v] @ kT_v^T, split-K=8 partials
    k_gemm_bt<3><<<dim3(4, 8, 24), 256, 0, stream>>>(
        kzT, MDIM, KZ, kzT, MDIM, KZ, MDIM / 8, 8,
        nullptr, 0, GWp, 512, (long)1024 * 512, nullptr, nullptr, nullptr);

    // 9: reduce partials -> G fp16, Bfin fp16
    k_rsplit<<<dim3(3 * 1024 * 512 / 256), 256, 0, stream>>>(
        GWp, G, Bfin, 3 * 1024 * 512);

    // 10: n2 = 0
    hipMemsetAsync(n2, 0, (size_t)3 * NROWS * 4, stream);

    // 11: n2_v[r] = (q G_v^T)_r . q_r, batched
    k_gemm_bt<4><<<dim3(4, 64, 3), 256, 0, stream>>>(
        q_h, HDIM, 0, G, HDIM, (long)512 * 512, HDIM, 0,
        nullptr, 0, nullptr, HDIM, 0, n2, q_h, nullptr);

    // 12: qs = per-view row-scaled q  [N][1536]
    k_scaleq<<<dim3(NROWS * 64 / 256), 256, 0, stream>>>(q_h, n2, qs);

    // 13: out = cz + qs @ Bfin^T   (K = 1536)
    k_gemm_bt<2><<<dim3(4, 64, 1), 256, 0, stream>>>(
        qs, 1536, 0, Bfin, 1536, 0, 1536, 0,
        nullptr, 0, out, FDIM, 0, nullptr, nullptr, cz);
}

// Round 5
// 282.710 us; speedup vs baseline: 3.8519x; 1.0811x over previous
//
#include <hip/hip_runtime.h>
#include <cstdint>

// Problem constants (from reference setup_inputs): N=M=8192, F=H=512, V=3.
#define NROWS 8192
#define MDIM  8192
#define FDIM  512
#define HDIM  512

typedef _Float16 f16x8_t __attribute__((ext_vector_type(8)));
typedef float    f32x4_t __attribute__((ext_vector_type(4)));
typedef int      i32x4_t __attribute__((ext_vector_type(4)));

__device__ __forceinline__ unsigned short f2h(float f) {
    return __builtin_bit_cast(unsigned short, (_Float16)f);
}
__device__ __forceinline__ float h2f(unsigned short u) {
    return (float)__builtin_bit_cast(_Float16, u);
}

// async global->LDS, 16B per lane; LDS dest = uniform base + lane*16
__device__ __forceinline__ void g2l16(const unsigned short* g, unsigned short* l) {
    __builtin_amdgcn_global_load_lds(
        (const __attribute__((address_space(1))) void*)g,
        (__attribute__((address_space(3))) void*)l, 16, 0, 0);
}

// ---- fp32 -> fp16 convert, 3 sources in one dispatch (z selects) ----
__global__ void k_cvt3(const float4* __restrict__ s0, ushort4* __restrict__ d0, int n0,
                       const float4* __restrict__ s1, ushort4* __restrict__ d1, int n1,
                       const float4* __restrict__ s2, ushort4* __restrict__ d2, int n2) {
    int i = blockIdx.x * blockDim.x + threadIdx.x;
    const float4* s; ushort4* d; int n;
    if (blockIdx.z == 0)      { s = s0; d = d0; n = n0; }
    else if (blockIdx.z == 1) { s = s1; d = d1; n = n1; }
    else                      { s = s2; d = d2; n = n2; }
    if (i < n) {
        float4 f = s[i];
        ushort4 u;
        u.x = f2h(f.x); u.y = f2h(f.y); u.z = f2h(f.z); u.w = f2h(f.w);
        d[i] = u;
    }
}

// ---- fp32 [R][C] -> fp16 row-major [R][C] AND fp16 transposed [C][R], batched z ----
__global__ void k_cvt_t(const float* __restrict__ src, long sV,
                        unsigned short* __restrict__ dn, long nV,
                        unsigned short* __restrict__ dt, long tV, int R, int C) {
    src += (long)blockIdx.z * sV; dn += (long)blockIdx.z * nV; dt += (long)blockIdx.z * tV;
    __shared__ unsigned short t[32][33];
    int c0 = blockIdx.x * 32, r0 = blockIdx.y * 32;
    #pragma unroll
    for (int k = 0; k < 32; k += 8) {
        unsigned short b = f2h(src[(size_t)(r0 + threadIdx.y + k) * C + c0 + threadIdx.x]);
        dn[(size_t)(r0 + threadIdx.y + k) * C + c0 + threadIdx.x] = b;
        t[threadIdx.y + k][threadIdx.x] = b;
    }
    __syncthreads();
    #pragma unroll
    for (int k = 0; k < 32; k += 8)
        dt[(size_t)(c0 + threadIdx.y + k) * R + r0 + threadIdx.x] =
            t[threadIdx.x][threadIdx.y + k];
}

// ---- reduce 8 split-K partials; rows<512 -> G fp16 [v][512][512],
//      rows>=512 -> Bfin fp16 [512][1536] (col = v*512 + h).
//      Also zeroes n2 (first 3*NROWS threads). ----
__global__ void k_rsplit(const float* __restrict__ GWp,
                         unsigned short* __restrict__ G,
                         unsigned short* __restrict__ Bfin,
                         float* __restrict__ n2, int n) {
    int i = blockIdx.x * blockDim.x + threadIdx.x;
    if (i >= n) return;
    if (i < 3 * NROWS) n2[i] = 0.f;
    int v = i / (1024 * 512);
    int rc = i - v * (1024 * 512);
    int row = rc >> 9, col = rc & 511;
    const float* p = GWp + (size_t)v * 8 * 1024 * 512 + rc;
    float s = 0.f;
    #pragma unroll
    for (int sl = 0; sl < 8; ++sl) s += p[(size_t)sl * 1024 * 512];
    if (row < 512) G[((size_t)v * 512 + row) * 512 + col] = f2h(s);
    else Bfin[(size_t)(row - 512) * 1536 + v * 512 + col] = f2h(s);
}

// ---- qs[r][v*512+h] = q[r][h] / max(sqrt(max(n2_v[r],0)), eps) ----
__global__ void k_scaleq(const unsigned short* __restrict__ q,
                         const float* __restrict__ n2,
                         unsigned short* __restrict__ qs) {
    int i = blockIdx.x * blockDim.x + threadIdx.x;  // NROWS*64 threads, 8 elems each
    int row = i >> 6, c8 = (i & 63) << 3;
    ushort4 a = *(const ushort4*)&q[(size_t)row * 512 + c8];
    ushort4 b = *(const ushort4*)&q[(size_t)row * 512 + c8 + 4];
    float qv[8] = {h2f(a.x), h2f(a.y), h2f(a.z), h2f(a.w),
                   h2f(b.x), h2f(b.y), h2f(b.z), h2f(b.w)};
    #pragma unroll
    for (int v = 0; v < 3; ++v) {
        float nn = n2[v * NROWS + row];
        float s = 1.f / fmaxf(sqrtf(fmaxf(nn, 0.f)), 1e-12f);
        ushort4 o0, o1;
        o0.x = f2h(s * qv[0]); o0.y = f2h(s * qv[1]);
        o0.z = f2h(s * qv[2]); o0.w = f2h(s * qv[3]);
        o1.x = f2h(s * qv[4]); o1.y = f2h(s * qv[5]);
        o1.z = f2h(s * qv[6]); o1.w = f2h(s * qv[7]);
        *(ushort4*)&qs[(size_t)row * 1536 + v * 512 + c8]     = o0;
        *(ushort4*)&qs[(size_t)row * 1536 + v * 512 + c8 + 4] = o1;
    }
}

// ---------------- fp16 GEMM, C[row][col] = sum_k A[row][k]*B[col][k] ----------------
// 128x128 tile, BK=64, 256 threads = 4 waves (64x64 quadrant each, 4x4 MFMA tiles).
// MODE 0: merged q/k GEMM. z=0: Cb = fp16(elu(acc)) row-major (q).
//         z>=1: Cb2 + (z-1)*cbV gets fp16(elu(acc)) TRANSPOSED (k^T), via per-wave
//         64x64 LDS transpose (XOR swizzle) + coalesced 128B writes.
// MODE 2: Cf = CZ + acc                              (final out GEMM, fp32)
// MODE 3: Cf[z] = acc  (per-(view,kslice) partials)  (G / Wvt split-K GEMM)
// MODE 4: atomicAdd(norms[view][row], sum_col acc*Q[row][col])   (n2 = (qG).q)
template<int MODE>
__global__ __launch_bounds__(256, 2)
void k_gemm_bt(const unsigned short* __restrict__ A, int lda, long aV,
               const unsigned short* __restrict__ B, int ldb, long bV,
               int K, int kslices,
               unsigned short* __restrict__ Cb, long cbV,
               float* __restrict__ Cf, int ldc, long cfV,
               float* __restrict__ norms,
               const unsigned short* __restrict__ Q,
               const float* __restrict__ CZ,
               const unsigned short* __restrict__ B2,
               unsigned short* __restrict__ Cb2) {
    const int z    = blockIdx.z;
    const int view = (MODE == 3) ? z / kslices : z;
    const int kbeg = (MODE == 3) ? (z % kslices) * K : 0;
    A += (long)view * aV;
    const unsigned short* Bp = (MODE == 0 && z > 0) ? B2 : B;
    Bp += (long)view * bV;

    __shared__ unsigned short S[2 * 128 * 64];
    unsigned short* As = S;
    unsigned short* Bs = S + 128 * 64;
    const int tid  = threadIdx.x;
    const int lane = tid & 63;
    const int w    = tid >> 6;
    const int wr   = w >> 1, wc = w & 1;
    const int row0 = blockIdx.y * 128;
    const int col0 = blockIdx.x * 128;
    const int quad = lane >> 4;
    const int l15  = lane & 15;
    const int srow = lane >> 3;
    const int scol = (lane & 7) * 8;
    const int wbase = w * 4;

    f32x4_t acc[4][4] = {};

    for (int k0 = kbeg; k0 < kbeg + K; k0 += 64) {
        __syncthreads();
        #pragma unroll
        for (int c = 0; c < 4; ++c) {
            int rr = (wbase + c) * 8 + srow;
            g2l16(A  + (size_t)(row0 + rr) * lda + k0 + scol, &As[(wbase + c) * 512]);
            g2l16(Bp + (size_t)(col0 + rr) * ldb + k0 + scol, &Bs[(wbase + c) * 512]);
        }
        asm volatile("s_waitcnt vmcnt(0)" ::: "memory");
        __syncthreads();
        #pragma unroll
        for (int kk = 0; kk < 2; ++kk) {
            f16x8_t af[4], bfr[4];
            #pragma unroll
            for (int i = 0; i < 4; ++i) {
                int r = wr * 64 + i * 16 + l15;
                af[i] = __builtin_bit_cast(f16x8_t,
                        *(const i32x4_t*)&As[r * 64 + kk * 32 + quad * 8]);
            }
            #pragma unroll
            for (int j = 0; j < 4; ++j) {
                int r = wc * 64 + j * 16 + l15;
                bfr[j] = __builtin_bit_cast(f16x8_t,
                        *(const i32x4_t*)&Bs[r * 64 + kk * 32 + quad * 8]);
            }
            #pragma unroll
            for (int i = 0; i < 4; ++i)
                #pragma unroll
                for (int j = 0; j < 4; ++j)
                    acc[i][j] = __builtin_amdgcn_mfma_f32_16x16x32_f16(
                        af[i], bfr[j], acc[i][j], 0, 0, 0);
        }
    }

    // C/D layout (m89-verified): col = lane&15, row = (lane>>4)*4 + reg
    if (MODE == 0) {
        if (z == 0) {
            #pragma unroll
            for (int i = 0; i < 4; ++i) {
                int rb = row0 + wr * 64 + i * 16 + quad * 4;
                #pragma unroll
                for (int j = 0; j < 4; ++j) {
                    int col = col0 + wc * 64 + j * 16 + l15;
                    #pragma unroll
                    for (int r = 0; r < 4; ++r) {
                        float v = acc[i][j][r];
                        v = v > 0.f ? v : expm1f(v);
                        Cb[(size_t)(rb + r) * ldc + col] = f2h(v);
                    }
                }
            }
        } else {
            // transposed epilogue: wave-local 64x64 tile -> LDS (XOR swizzle) -> k^T
            __syncthreads();               // all waves done reading As/Bs
            unsigned short* T = S + w * 4096;   // 8KB slab per wave
            #pragma unroll
            for (int i = 0; i < 4; ++i)
                #pragma unroll
                for (int j = 0; j < 4; ++j) {
                    int ct = j * 16 + l15;
                    #pragma unroll
                    for (int r = 0; r < 4; ++r) {
                        int rt = i * 16 + quad * 4 + r;
                        float v = acc[i][j][r];
                        v = v > 0.f ? v : expm1f(v);
                        T[ct * 64 + (rt ^ ((ct & 7) << 3))] = f2h(v);
                    }
                }
            // wave-internal LDS dependency only; compiler inserts lgkmcnt waits
            unsigned short* dst = Cb2 + (long)(z - 1) * cbV;
            #pragma unroll
            for (int it = 0; it < 8; ++it) {
                int c  = it * 8 + (lane >> 3);
                int rg = (lane & 7) * 8;
                i32x4_t val = *(const i32x4_t*)&T[c * 64 + (rg ^ ((c & 7) << 3))];
                *(i32x4_t*)&dst[(size_t)(col0 + wc * 64 + c) * MDIM
                                + row0 + wr * 64 + rg] = val;
            }
        }
    } else if (MODE == 2) {
        #pragma unroll
        for (int i = 0; i < 4; ++i) {
            #pragma unroll
            for (int r = 0; r < 4; ++r) {
                int row = row0 + wr * 64 + i * 16 + quad * 4 + r;
                #pragma unroll
                for (int j = 0; j < 4; ++j) {
                    int col = col0 + wc * 64 + j * 16 + l15;
                    Cf[(size_t)row * ldc + col] =
                        CZ[(size_t)row * ldc + col] + acc[i][j][r];
                }
            }
        }
    } else if (MODE == 3) {
        float* C = Cf + (long)z * cfV;
        #pragma unroll
        for (int i = 0; i < 4; ++i) {
            int rb = row0 + wr * 64 + i * 16 + quad * 4;
            #pragma unroll
            for (int j = 0; j < 4; ++j) {
                int col = col0 + wc * 64 + j * 16 + l15;
                #pragma unroll
                for (int r = 0; r < 4; ++r)
                    C[(size_t)(rb + r) * ldc + col] = acc[i][j][r];
            }
        }
    } else if (MODE == 4) {
        float* nptr = norms + (long)view * NROWS;
        float rs[4][4] = {};
        #pragma unroll
        for (int i = 0; i < 4; ++i) {
            int rb = row0 + wr * 64 + i * 16 + quad * 4;
            #pragma unroll
            for (int j = 0; j < 4; ++j) {
                int col = col0 + wc * 64 + j * 16 + l15;
                #pragma unroll
                for (int r = 0; r < 4; ++r)
                    rs[i][r] += acc[i][j][r] * h2f(Q[(size_t)(rb + r) * ldc + col]);
            }
        }
        #pragma unroll
        for (int i = 0; i < 4; ++i)
            #pragma unroll
            for (int r = 0; r < 4; ++r) {
                float v = rs[i][r];
                v += __shfl_xor(v, 1);
                v += __shfl_xor(v, 2);
                v += __shfl_xor(v, 4);
                v += __shfl_xor(v, 8);
                if (l15 == 0)
                    atomicAdd(&nptr[row0 + wr * 64 + i * 16 + quad * 4 + r], v);
            }
    }
}

extern "C" void kernel_launch(void* const* d_in, const int* in_sizes, int n_in,
                              void* d_out, int out_size, void* d_ws, size_t ws_size,
                              hipStream_t stream) {
    const float* cz = (const float*)d_in[0];
    const float* zs = (const float*)d_in[1];
    const float* Wq = (const float*)d_in[2];
    const float* Wk = (const float*)d_in[3];
    float* out = (float*)d_out;

    char* ws = (char*)d_ws;
    size_t off = 0;
    auto alloc = [&](size_t bytes) -> void* {
        void* p = ws + off;
        off += (bytes + 255) & ~(size_t)255;
        return p;
    };
    const long MF = (long)MDIM * FDIM;   // 8192*512
    const long KZ = (long)1024 * MDIM;   // per-view kzT stride

    unsigned short* X_h   = (unsigned short*)alloc((size_t)4 * MF * 2);          // 32 MB: [cz; zv0..2]
    unsigned short* wq_h  = (unsigned short*)alloc((size_t)HDIM * FDIM * 2);
    unsigned short* wk_h  = (unsigned short*)alloc((size_t)HDIM * FDIM * 2);
    unsigned short* q_h   = (unsigned short*)alloc((size_t)NROWS * HDIM * 2);    // 8 MB
    unsigned short* kzT   = (unsigned short*)alloc((size_t)3 * KZ * 2);          // 48 MB: [kT; zvT]/view
    float* GWp            = (float*)alloc((size_t)3 * 8 * 1024 * 512 * 4);       // 48 MB
    unsigned short* G     = (unsigned short*)alloc((size_t)3 * 512 * 512 * 2);
    unsigned short* Bfin  = (unsigned short*)alloc((size_t)512 * 1536 * 2);
    float* n2             = (float*)alloc((size_t)3 * NROWS * 4);
    unsigned short* qs    = (unsigned short*)alloc((size_t)NROWS * 1536 * 2);    // 24 MB

    // 1: cz -> X_h[0], Wq -> wq_h, Wk -> wk_h  (one dispatch, z=3)
    k_cvt3<<<dim3(NROWS * FDIM / 4 / 256, 1, 3), 256, 0, stream>>>(
        (const float4*)cz, (ushort4*)X_h, NROWS * FDIM / 4,
        (const float4*)Wq, (ushort4*)wq_h, HDIM * FDIM / 4,
        (const float4*)Wk, (ushort4*)wk_h, HDIM * FDIM / 4);

    // 2: zs -> X_h[1..3] (row-major) + zvT into kzT upper half, all views
    k_cvt_t<<<dim3(FDIM / 32, MDIM / 32, 3), dim3(32, 8), 0, stream>>>(
        zs, MF, X_h + MF, MF, kzT + (size_t)512 * MDIM, KZ, MDIM, FDIM);

    // 3: z=0: q = elu(cz@Wq^T) -> q_h; z=1..3: kT_v = elu(zv@Wk^T)^T -> kzT lower half
    k_gemm_bt<0><<<dim3(4, 64, 4), 256, 0, stream>>>(
        X_h, FDIM, MF, wq_h, FDIM, 0, FDIM, 0,
        q_h, KZ, nullptr, HDIM, 0, nullptr, nullptr, nullptr, wk_h, kzT);

    // 4: [G_v; Wvt_v] = [kT_v; zvT_v] @ kT_v^T, split-K=8 partials
    k_gemm_bt<3><<<dim3(4, 8, 24), 256, 0, stream>>>(
        kzT, MDIM, KZ, kzT, MDIM, KZ, MDIM / 8, 8,
        nullptr, 0, GWp, 512, (long)1024 * 512, nullptr, nullptr, nullptr,
        nullptr, nullptr);

    // 5: reduce partials -> G fp16, Bfin fp16; zero n2
    k_rsplit<<<dim3(3 * 1024 * 512 / 256), 256, 0, stream>>>(
        GWp, G, Bfin, n2, 3 * 1024 * 512);

    // 6: n2_v[r] = (q G_v^T)_r . q_r, batched
    k_gemm_bt<4><<<dim3(4, 64, 3), 256, 0, stream>>>(
        q_h, HDIM, 0, G, HDIM, (long)512 * 512, HDIM, 0,
        nullptr, 0, nullptr, HDIM, 0, n2, q_h, nullptr, nullptr, nullptr);

    // 7: qs = per-view row-scaled q  [N][1536]
    k_scaleq<<<dim3(NROWS * 64 / 256), 256, 0, stream>>>(q_h, n2, qs);

    // 8: out = cz + qs @ Bfin^T   (K = 1536)
    k_gemm_bt<2><<<dim3(4, 64, 1), 256, 0, stream>>>(
        qs, 1536, 0, Bfin, 1536, 0, 1536, 0,
        nullptr, 0, out, FDIM, 0, nullptr, nullptr, cz, nullptr, nullptr);
}

// Round 6
// 251.829 us; speedup vs baseline: 4.3242x; 1.1226x over previous
//
#include <hip/hip_runtime.h>
#include <cstdint>

// Problem constants (from reference setup_inputs): N=M=8192, F=H=512, V=3.
#define NROWS 8192
#define MDIM  8192
#define FDIM  512
#define HDIM  512
#define GWSPLIT 4

typedef _Float16 f16x8_t __attribute__((ext_vector_type(8)));
typedef float    f32x4_t __attribute__((ext_vector_type(4)));
typedef int      i32x4_t __attribute__((ext_vector_type(4)));

__device__ __forceinline__ unsigned short f2h(float f) {
    return __builtin_bit_cast(unsigned short, (_Float16)f);
}
__device__ __forceinline__ float h2f(unsigned short u) {
    return (float)__builtin_bit_cast(_Float16, u);
}

// async global->LDS, 16B per lane; LDS dest = uniform base + lane*16
__device__ __forceinline__ void g2l16(const unsigned short* g, unsigned short* l) {
    __builtin_amdgcn_global_load_lds(
        (const __attribute__((address_space(1))) void*)g,
        (__attribute__((address_space(3))) void*)l, 16, 0, 0);
}

// ---- one-dispatch prep: z=0..2 view cvt+transpose, z=3 cz cvt, z=4 Wq/Wk cvt ----
__global__ void k_prep(const float* __restrict__ zs,
                       unsigned short* __restrict__ zn,       // X_h + MF (row-major views)
                       unsigned short* __restrict__ zt, long tV,  // kzT upper half
                       const float* __restrict__ cz, unsigned short* __restrict__ cz_h,
                       const float* __restrict__ Wq, unsigned short* __restrict__ wq_h,
                       const float* __restrict__ Wk, unsigned short* __restrict__ wk_h) {
    const long MF = (long)MDIM * FDIM;
    int z = blockIdx.z;
    if (z < 3) {
        const float* src = zs + (long)z * MF;
        unsigned short* dn = zn + (long)z * MF;
        unsigned short* dt = zt + (long)z * tV;
        __shared__ unsigned short t[32][33];
        int c0 = blockIdx.x * 32, r0 = blockIdx.y * 32;
        #pragma unroll
        for (int k = 0; k < 32; k += 8) {
            unsigned short b = f2h(src[(size_t)(r0 + threadIdx.y + k) * FDIM + c0 + threadIdx.x]);
            dn[(size_t)(r0 + threadIdx.y + k) * FDIM + c0 + threadIdx.x] = b;
            t[threadIdx.y + k][threadIdx.x] = b;
        }
        __syncthreads();
        #pragma unroll
        for (int k = 0; k < 32; k += 8)
            dt[(size_t)(c0 + threadIdx.y + k) * MDIM + r0 + threadIdx.x] =
                t[threadIdx.x][threadIdx.y + k];
    } else {
        int tid = threadIdx.y * 32 + threadIdx.x;             // 0..255
        int b = blockIdx.y * gridDim.x + blockIdx.x;          // 0..4095
        if (z == 3) {
            int i = b * 256 + tid;                            // NROWS*FDIM/4 = 1,048,576
            float4 f = ((const float4*)cz)[i];
            ushort4 u;
            u.x = f2h(f.x); u.y = f2h(f.y); u.z = f2h(f.z); u.w = f2h(f.w);
            ((ushort4*)cz_h)[i] = u;
        } else if (b < 512) {
            const float4* s = (b < 256) ? (const float4*)Wq : (const float4*)Wk;
            ushort4* d = (b < 256) ? (ushort4*)wq_h : (ushort4*)wk_h;
            int i = (b & 255) * 256 + tid;                    // 65536 per matrix
            float4 f = s[i];
            ushort4 u;
            u.x = f2h(f.x); u.y = f2h(f.y); u.z = f2h(f.z); u.w = f2h(f.w);
            d[i] = u;
        }
    }
}

// ---- reduce GWSPLIT split-K partials; rows<512 -> G fp16 [v][512][512],
//      rows>=512 -> Bfin fp16 [512][1536] (col = v*512+h). Zeroes n2. ----
__global__ void k_rsplit(const float* __restrict__ GWp,
                         unsigned short* __restrict__ G,
                         unsigned short* __restrict__ Bfin,
                         float* __restrict__ n2, int n) {
    int i = blockIdx.x * blockDim.x + threadIdx.x;
    if (i >= n) return;
    if (i < 3 * NROWS) n2[i] = 0.f;
    int v = i / (1024 * 512);
    int rc = i - v * (1024 * 512);
    int row = rc >> 9, col = rc & 511;
    const float* p = GWp + (size_t)v * GWSPLIT * 1024 * 512 + rc;
    float s = 0.f;
    #pragma unroll
    for (int sl = 0; sl < GWSPLIT; ++sl) s += p[(size_t)sl * 1024 * 512];
    if (row < 512) G[((size_t)v * 512 + row) * 512 + col] = f2h(s);
    else Bfin[(size_t)(row - 512) * 1536 + v * 512 + col] = f2h(s);
}

// ---------------- fp16 GEMM, C[row][col] = sum_k A[row][k]*B[col][k] ----------------
// 128x128 tile, BK=64, 256 threads = 4 waves (64x64 quadrant each, 4x4 MFMA tiles).
// LDS XOR-swizzle: LDS slot (row, c) holds global chunk c^(row&7) (16B chunks), so
// fragment ds_read_b128 hits 8 distinct bank groups (2-way only = free).
// MODE 0: merged q/k GEMM. z=0: Cb = fp16(elu(acc)) row-major (q).
//         z>=1: Cb2+(z-1)*cbV = fp16(elu(acc)) TRANSPOSED (k^T) via LDS.
// MODE 2: Cf = CZ + acc, with A-fragments scaled per (row, view=k/512) by
//         1/max(sqrt(n2),eps)   (fused scaleq + final out GEMM; A wraps k&akmask)
// MODE 3: Cf[z] = acc  (per-(view,kslice) partials)   (G / Wvt split-K GEMM)
// MODE 4: atomicAdd(norms[view][row], sum_col acc*Q[row][col])    (n2 = (qG).q)
template<int MODE>
__global__ __launch_bounds__(256, 2)
void k_gemm_bt(const unsigned short* __restrict__ A, int lda, long aV, int akmask,
               const unsigned short* __restrict__ B, int ldb, long bV,
               int K, int kslices,
               unsigned short* __restrict__ Cb, long cbV,
               float* __restrict__ Cf, int ldc, long cfV,
               float* __restrict__ norms,
               const unsigned short* __restrict__ Q,
               const float* __restrict__ CZ,
               const unsigned short* __restrict__ B2,
               unsigned short* __restrict__ Cb2) {
    const int z    = blockIdx.z;
    const int view = (MODE == 3) ? z / kslices : z;
    const int kbeg = (MODE == 3) ? (z % kslices) * K : 0;
    A += (long)view * aV;
    const unsigned short* Bp = (MODE == 0 && z > 0) ? B2 : B;
    Bp += (long)view * bV;

    __shared__ unsigned short S[2 * 128 * 64];
    unsigned short* As = S;
    unsigned short* Bs = S + 128 * 64;
    const int tid  = threadIdx.x;
    const int lane = tid & 63;
    const int w    = tid >> 6;
    const int wr   = w >> 1, wc = w & 1;
    const int row0 = blockIdx.y * 128;
    const int col0 = blockIdx.x * 128;
    const int quad = lane >> 4;
    const int l15  = lane & 15;
    const int srow = lane >> 3;                 // 0..7
    const int scol = (((lane & 7) ^ srow) * 8); // XOR-swizzled global chunk
    const int wbase = w * 4;

    // MODE2: per-row per-view scales for A fragments
    _Float16 sch[3][4];
    if (MODE == 2) {
        #pragma unroll
        for (int v = 0; v < 3; ++v)
            #pragma unroll
            for (int i = 0; i < 4; ++i) {
                int row = row0 + wr * 64 + i * 16 + l15;
                float nn = norms[v * NROWS + row];
                float s = 1.f / fmaxf(sqrtf(fmaxf(nn, 0.f)), 1e-12f);
                sch[v][i] = (_Float16)fminf(s, 60000.f);
            }
    }

    f32x4_t acc[4][4] = {};

    for (int k0 = kbeg; k0 < kbeg + K; k0 += 64) {
        __syncthreads();
        const int ka = k0 & akmask;
        #pragma unroll
        for (int c = 0; c < 4; ++c) {
            int rr = (wbase + c) * 8 + srow;
            g2l16(A  + (size_t)(row0 + rr) * lda + ka + scol, &As[(wbase + c) * 512]);
            g2l16(Bp + (size_t)(col0 + rr) * ldb + k0 + scol, &Bs[(wbase + c) * 512]);
        }
        asm volatile("s_waitcnt vmcnt(0)" ::: "memory");
        __syncthreads();
        #pragma unroll
        for (int kk = 0; kk < 2; ++kk) {
            f16x8_t af[4], bfr[4];
            #pragma unroll
            for (int i = 0; i < 4; ++i) {
                int r = wr * 64 + i * 16 + l15;
                af[i] = __builtin_bit_cast(f16x8_t,
                        *(const i32x4_t*)&As[r * 64 + (((kk * 4 + quad) ^ (r & 7)) << 3)]);
            }
            if (MODE == 2) {
                int vw = k0 >> 9;
                #pragma unroll
                for (int i = 0; i < 4; ++i) af[i] = af[i] * sch[vw][i];
            }
            #pragma unroll
            for (int j = 0; j < 4; ++j) {
                int r = wc * 64 + j * 16 + l15;
                bfr[j] = __builtin_bit_cast(f16x8_t,
                        *(const i32x4_t*)&Bs[r * 64 + (((kk * 4 + quad) ^ (r & 7)) << 3)]);
            }
            #pragma unroll
            for (int i = 0; i < 4; ++i)
                #pragma unroll
                for (int j = 0; j < 4; ++j)
                    acc[i][j] = __builtin_amdgcn_mfma_f32_16x16x32_f16(
                        af[i], bfr[j], acc[i][j], 0, 0, 0);
        }
    }

    // C/D layout (m89-verified): col = lane&15, row = (lane>>4)*4 + reg
    if (MODE == 0) {
        if (z == 0) {
            #pragma unroll
            for (int i = 0; i < 4; ++i) {
                int rb = row0 + wr * 64 + i * 16 + quad * 4;
                #pragma unroll
                for (int j = 0; j < 4; ++j) {
                    int col = col0 + wc * 64 + j * 16 + l15;
                    #pragma unroll
                    for (int r = 0; r < 4; ++r) {
                        float v = acc[i][j][r];
                        v = v > 0.f ? v : expm1f(v);
                        Cb[(size_t)(rb + r) * ldc + col] = f2h(v);
                    }
                }
            }
        } else {
            // transposed epilogue: wave-local 64x64 tile -> LDS (XOR swizzle) -> k^T
            __syncthreads();               // all waves done reading As/Bs
            unsigned short* T = S + w * 4096;   // 8KB slab per wave
            #pragma unroll
            for (int i = 0; i < 4; ++i)
                #pragma unroll
                for (int j = 0; j < 4; ++j) {
                    int ct = j * 16 + l15;
                    #pragma unroll
                    for (int r = 0; r < 4; ++r) {
                        int rt = i * 16 + quad * 4 + r;
                        float v = acc[i][j][r];
                        v = v > 0.f ? v : expm1f(v);
                        T[ct * 64 + (rt ^ ((ct & 7) << 3))] = f2h(v);
                    }
                }
            unsigned short* dst = Cb2 + (long)(z - 1) * cbV;
            #pragma unroll
            for (int it = 0; it < 8; ++it) {
                int c  = it * 8 + (lane >> 3);
                int rg = (lane & 7) * 8;
                i32x4_t val = *(const i32x4_t*)&T[c * 64 + (rg ^ ((c & 7) << 3))];
                *(i32x4_t*)&dst[(size_t)(col0 + wc * 64 + c) * MDIM
                                + row0 + wr * 64 + rg] = val;
            }
        }
    } else if (MODE == 2) {
        #pragma unroll
        for (int i = 0; i < 4; ++i) {
            #pragma unroll
            for (int r = 0; r < 4; ++r) {
                int row = row0 + wr * 64 + i * 16 + quad * 4 + r;
                #pragma unroll
                for (int j = 0; j < 4; ++j) {
                    int col = col0 + wc * 64 + j * 16 + l15;
                    Cf[(size_t)row * ldc + col] =
                        CZ[(size_t)row * ldc + col] + acc[i][j][r];
                }
            }
        }
    } else if (MODE == 3) {
        float* C = Cf + (long)z * cfV;
        #pragma unroll
        for (int i = 0; i < 4; ++i) {
            int rb = row0 + wr * 64 + i * 16 + quad * 4;
            #pragma unroll
            for (int j = 0; j < 4; ++j) {
                int col = col0 + wc * 64 + j * 16 + l15;
                #pragma unroll
                for (int r = 0; r < 4; ++r)
                    C[(size_t)(rb + r) * ldc + col] = acc[i][j][r];
            }
        }
    } else if (MODE == 4) {
        float* nptr = norms + (long)view * NROWS;
        float rs[4][4] = {};
        #pragma unroll
        for (int i = 0; i < 4; ++i) {
            int rb = row0 + wr * 64 + i * 16 + quad * 4;
            #pragma unroll
            for (int j = 0; j < 4; ++j) {
                int col = col0 + wc * 64 + j * 16 + l15;
                #pragma unroll
                for (int r = 0; r < 4; ++r)
                    rs[i][r] += acc[i][j][r] * h2f(Q[(size_t)(rb + r) * ldc + col]);
            }
        }
        #pragma unroll
        for (int i = 0; i < 4; ++i)
            #pragma unroll
            for (int r = 0; r < 4; ++r) {
                float v = rs[i][r];
                v += __shfl_xor(v, 1);
                v += __shfl_xor(v, 2);
                v += __shfl_xor(v, 4);
                v += __shfl_xor(v, 8);
                if (l15 == 0)
                    atomicAdd(&nptr[row0 + wr * 64 + i * 16 + quad * 4 + r], v);
            }
    }
}

extern "C" void kernel_launch(void* const* d_in, const int* in_sizes, int n_in,
                              void* d_out, int out_size, void* d_ws, size_t ws_size,
                              hipStream_t stream) {
    const float* cz = (const float*)d_in[0];
    const float* zs = (const float*)d_in[1];
    const float* Wq = (const float*)d_in[2];
    const float* Wk = (const float*)d_in[3];
    float* out = (float*)d_out;
    const int NOMASK = 0x7fffffff;

    char* ws = (char*)d_ws;
    size_t off = 0;
    auto alloc = [&](size_t bytes) -> void* {
        void* p = ws + off;
        off += (bytes + 255) & ~(size_t)255;
        return p;
    };
    const long MF = (long)MDIM * FDIM;   // 8192*512
    const long KZ = (long)1024 * MDIM;   // per-view kzT stride

    unsigned short* X_h   = (unsigned short*)alloc((size_t)4 * MF * 2);          // 32 MB: [cz; zv0..2]
    unsigned short* wq_h  = (unsigned short*)alloc((size_t)HDIM * FDIM * 2);
    unsigned short* wk_h  = (unsigned short*)alloc((size_t)HDIM * FDIM * 2);
    unsigned short* q_h   = (unsigned short*)alloc((size_t)NROWS * HDIM * 2);    // 8 MB
    unsigned short* kzT   = (unsigned short*)alloc((size_t)3 * KZ * 2);          // 48 MB: [kT; zvT]/view
    float* GWp            = (float*)alloc((size_t)3 * GWSPLIT * 1024 * 512 * 4); // 24 MB
    unsigned short* G     = (unsigned short*)alloc((size_t)3 * 512 * 512 * 2);
    unsigned short* Bfin  = (unsigned short*)alloc((size_t)512 * 1536 * 2);
    float* n2             = (float*)alloc((size_t)3 * NROWS * 4);

    // 1: all input converts + zvT transpose (z=0..2 views, z=3 cz, z=4 Wq/Wk)
    k_prep<<<dim3(FDIM / 32, MDIM / 32, 5), dim3(32, 8), 0, stream>>>(
        zs, X_h + MF, kzT + (size_t)512 * MDIM, KZ,
        cz, X_h, Wq, wq_h, Wk, wk_h);

    // 2: z=0: q = elu(cz@Wq^T) -> q_h; z=1..3: kT_v = elu(zv@Wk^T)^T -> kzT lower half
    k_gemm_bt<0><<<dim3(4, 64, 4), 256, 0, stream>>>(
        X_h, FDIM, MF, NOMASK, wq_h, FDIM, 0, FDIM, 0,
        q_h, KZ, nullptr, HDIM, 0, nullptr, nullptr, nullptr, wk_h, kzT);

    // 3: [G_v; Wvt_v] = [kT_v; zvT_v] @ kT_v^T, split-K=GWSPLIT partials
    k_gemm_bt<3><<<dim3(4, 8, 3 * GWSPLIT), 256, 0, stream>>>(
        kzT, MDIM, KZ, NOMASK, kzT, MDIM, KZ, MDIM / GWSPLIT, GWSPLIT,
        nullptr, 0, GWp, 512, (long)1024 * 512, nullptr, nullptr, nullptr,
        nullptr, nullptr);

    // 4: reduce partials -> G fp16, Bfin fp16; zero n2
    k_rsplit<<<dim3(3 * 1024 * 512 / 256), 256, 0, stream>>>(
        GWp, G, Bfin, n2, 3 * 1024 * 512);

    // 5: n2_v[r] = (q G_v^T)_r . q_r, batched
    k_gemm_bt<4><<<dim3(4, 64, 3), 256, 0, stream>>>(
        q_h, HDIM, 0, NOMASK, G, HDIM, (long)512 * 512, HDIM, 0,
        nullptr, 0, nullptr, HDIM, 0, n2, q_h, nullptr, nullptr, nullptr);

    // 6: out = cz + sum_v s_v(row) * (q @ Wvt_v^T)   (K=1536, A wraps k&511,
    //    per-view per-row scale fused into A fragments)
    k_gemm_bt<2><<<dim3(4, 64, 1), 256, 0, stream>>>(
        q_h, HDIM, 0, 511, Bfin, 1536, 0, 1536, 0,
        nullptr, 0, out, FDIM, 0, n2, nullptr, cz, nullptr, nullptr);
}